// Round 7
// baseline (344.520 us; speedup 1.0000x reference)
//
#include <hip/hip_runtime.h>
#include <hip/hip_cooperative_groups.h>

namespace cg = cooperative_groups;

#define N_NODES 100000
#define D_FEAT 128
#define N_CLASSES 32
#define BSHIFT 8
#define NB 391            // ceil(100000/256) dst buckets of 256 nodes
#define EPB 4096          // edges per partition unit (391 units for E=1.6M)
#define CAPB 5120         // per-bucket region capacity (mean 4092 + >8 sigma)
#define GCAP 1536         // per-quarter sorted capacity (mean 1023 + >8 sigma)
#define PUNITS 1563       // projection units (64 nodes each)
#define NGU (NB * 4)      // gather quarter-units

typedef __attribute__((ext_vector_type(8))) short short8;
typedef __attribute__((ext_vector_type(4))) float f32x4;

// pack two f32 -> two bf16 (RNE) in one instruction
__device__ __forceinline__ unsigned cvtpk(float lo, float hi) {
  unsigned r;
  asm("v_cvt_pk_bf16_f32 %0, %1, %2" : "=v"(r) : "v"(lo), "v"(hi));
  return r;
}
__device__ __forceinline__ float bflo(unsigned v) { return __uint_as_float(v << 16); }
__device__ __forceinline__ float bfhi(unsigned v) { return __uint_as_float(v & 0xFFFF0000u); }

// ---------- projection unit: 64 nodes, 4 waves x 16 nodes x 32 classes ----------
// W converted f32->bf16 in registers (16 KB table, L2-hot; kills the Wb prep).
// Writes f32 y (exact self-term) and bf16 yh (gather aggregate table).
__device__ __forceinline__ void proj_unit(int pb, int tid,
    const float* __restrict__ x, const float* __restrict__ W,
    float* __restrict__ y, unsigned short* __restrict__ yh) {
  int wave = tid >> 6, lane = tid & 63;
  int node_base = pb * 64 + wave * 16;
  if (node_base >= N_NODES) return;
  int m = lane & 15, quad = lane >> 4;

  short8 bfrag[2][4];
#pragma unroll
  for (int cb = 0; cb < 2; ++cb) {
    const float* wr = W + (cb * 16 + m) * D_FEAT + quad * 8;
#pragma unroll
    for (int ks = 0; ks < 4; ++ks) {
      float4 g0 = *(const float4*)(wr + ks * 32);
      float4 g1 = *(const float4*)(wr + ks * 32 + 4);
      union { uint4 u; short8 s; } bu;
      bu.u.x = cvtpk(g0.x, g0.y);
      bu.u.y = cvtpk(g0.z, g0.w);
      bu.u.z = cvtpk(g1.x, g1.y);
      bu.u.w = cvtpk(g1.z, g1.w);
      bfrag[cb][ks] = bu.s;
    }
  }

  const float* xr = x + (size_t)(node_base + m) * D_FEAT + quad * 8;
  short8 afrag[4];
#pragma unroll
  for (int ks = 0; ks < 4; ++ks) {
    float4 f0 = *(const float4*)(xr + ks * 32);
    float4 f1 = *(const float4*)(xr + ks * 32 + 4);
    union { uint4 u; short8 s; } au;
    au.u.x = cvtpk(f0.x, f0.y);
    au.u.y = cvtpk(f0.z, f0.w);
    au.u.z = cvtpk(f1.x, f1.y);
    au.u.w = cvtpk(f1.z, f1.w);
    afrag[ks] = au.s;
  }

  f32x4 acc0 = {0.f, 0.f, 0.f, 0.f};
  f32x4 acc1 = {0.f, 0.f, 0.f, 0.f};
#pragma unroll
  for (int ks = 0; ks < 4; ++ks) {
    acc0 = __builtin_amdgcn_mfma_f32_16x16x32_bf16(afrag[ks], bfrag[0][ks], acc0, 0, 0, 0);
    acc1 = __builtin_amdgcn_mfma_f32_16x16x32_bf16(afrag[ks], bfrag[1][ks], acc1, 0, 0, 0);
  }

#pragma unroll
  for (int r = 0; r < 4; ++r) {
    int node = node_base + quad * 4 + r;
    y[(size_t)node * N_CLASSES + m] = acc0[r];
    y[(size_t)node * N_CLASSES + 16 + m] = acc1[r];
    unsigned pk = cvtpk(acc0[r], acc1[r]);
    yh[(size_t)node * N_CLASSES + m] = (unsigned short)(pk & 0xFFFFu);
    yh[(size_t)node * N_CLASSES + 16 + m] = (unsigned short)(pk >> 16);
  }
}

// ---------- partition unit: 4096 edges -> 256-node buckets (round-5 proven) ----------
__device__ __forceinline__ void partition_unit(int blk, int tid, int E,
    const int* __restrict__ src, const int* __restrict__ dst,
    int* __restrict__ gcount, unsigned* __restrict__ bucketed,
    int* cnt, int* cur, int* gbase) {
  for (int i = tid; i < NB; i += 256) { cnt[i] = 0; cur[i] = 0; }
  __syncthreads();
  int base = blk * EPB;
  bool full = (base + EPB <= E);
  int dv[16];
  unsigned sv[16];
  if (full) {
#pragma unroll
    for (int k = 0; k < 16; ++k) dv[k] = dst[base + k * 256 + tid];
#pragma unroll
    for (int k = 0; k < 16; ++k) sv[k] = (unsigned)src[base + k * 256 + tid];
  } else {
#pragma unroll
    for (int k = 0; k < 16; ++k) {
      int e = base + k * 256 + tid;
      dv[k] = (e < E) ? dst[e] : -1;
      sv[k] = (e < E) ? (unsigned)src[e] : 0u;
    }
  }
#pragma unroll
  for (int k = 0; k < 16; ++k)
    if (dv[k] >= 0) atomicAdd(&cnt[dv[k] >> BSHIFT], 1);
  __syncthreads();
  // reserve global ranges (within-bucket order irrelevant -> no scan anywhere)
  for (int i = tid; i < NB; i += 256) {
    int c = cnt[i];
    gbase[i] = c ? atomicAdd(&gcount[i], c) : 0;
  }
  __syncthreads();
  // direct scattered store: runs of ~10.5 consecutive slots per bucket (~2x amp)
#pragma unroll
  for (int k = 0; k < 16; ++k) {
    if (dv[k] >= 0) {
      int b = dv[k] >> BSHIFT;
      int r = atomicAdd(&cur[b], 1);
      int ga = gbase[b] + r;
      if (ga < CAPB)
        bucketed[(size_t)b * CAPB + ga] = sv[k] | ((unsigned)(dv[k] & 255) << 17);
    }
  }
}

// ---------- gather unit: one 64-node quarter of a 256-node bucket ----------
// Stage bucket into LDS (single global pass) + count own quarter, scan, LDS
// counting-scatter, then 4-threads-per-node accumulation from bf16 yh (each
// thread reads uint4 = 8 classes; 4 threads cover the 64 B row coalesced).
__device__ __forceinline__ void gather_unit(int gu, int tid,
    const int* __restrict__ gcount, const unsigned* __restrict__ bucketed,
    const float* __restrict__ y, const unsigned short* __restrict__ yh,
    const float* __restrict__ bias, float* __restrict__ out,
    unsigned* stage, unsigned* sorted, int* cnt, int* off, int* cur) {
  int bk = gu >> 2, qq = gu & 3;
  int len = gcount[bk];
  if (len > CAPB) len = CAPB;
  const unsigned* bb = bucketed + (size_t)bk * CAPB;
  if (tid < 64) cnt[tid] = 0;
  __syncthreads();
  for (int i = tid; i < len; i += 256) {
    unsigned p = bb[i];
    stage[i] = p;
    int n8 = (int)((p >> 17) & 255u);
    if ((n8 >> 6) == qq) atomicAdd(&cnt[n8 & 63], 1);
  }
  __syncthreads();
  if (tid == 0) off[0] = 0;
  if (tid < 64) off[tid + 1] = cnt[tid];
  __syncthreads();
  for (int o = 1; o < 64; o <<= 1) {
    int v = (tid < 64 && tid >= o) ? off[tid + 1 - o] : 0;
    __syncthreads();
    if (tid < 64) off[tid + 1] += v;
    __syncthreads();
  }
  if (tid < 64) cur[tid] = off[tid];
  __syncthreads();
  for (int i = tid; i < len; i += 256) {
    unsigned p = stage[i];
    int n8 = (int)((p >> 17) & 255u);
    if ((n8 >> 6) == qq) {
      int pos = atomicAdd(&cur[n8 & 63], 1);
      if (pos < GCAP) sorted[pos] = p;
    }
  }
  __syncthreads();
  int nl = tid >> 2, q4 = tid & 3;
  int es = off[nl], ee = off[nl + 1];
  if (ee > GCAP) ee = GCAP;
  if (es > ee) es = ee;
  int node = (bk << 8) + (qq << 6) + nl;
  if (node >= N_NODES) return;
  const uint4* yh4 = (const uint4*)yh;     // row = 4 uint4 (32 bf16)
  const float4* y4 = (const float4*)y;
  float4 sA = y4[(size_t)node * 8 + q4 * 2];
  float4 sB = y4[(size_t)node * 8 + q4 * 2 + 1];
  float4 bA = ((const float4*)bias)[q4 * 2];
  float4 bB = ((const float4*)bias)[q4 * 2 + 1];
  float4 accA = {sA.x + bA.x, sA.y + bA.y, sA.z + bA.z, sA.w + bA.w};
  float4 accB = {sB.x + bB.x, sB.y + bB.y, sB.z + bB.z, sB.w + bB.w};
  int j = es;
  for (; j + 2 <= ee; j += 2) {
    unsigned s0 = sorted[j] & 0x1FFFF, s1 = sorted[j + 1] & 0x1FFFF;
    uint4 v0 = yh4[(size_t)s0 * 4 + q4];
    uint4 v1 = yh4[(size_t)s1 * 4 + q4];
    accA.x += bflo(v0.x) + bflo(v1.x);
    accA.y += bfhi(v0.x) + bfhi(v1.x);
    accA.z += bflo(v0.y) + bflo(v1.y);
    accA.w += bfhi(v0.y) + bfhi(v1.y);
    accB.x += bflo(v0.z) + bflo(v1.z);
    accB.y += bfhi(v0.z) + bfhi(v1.z);
    accB.z += bflo(v0.w) + bflo(v1.w);
    accB.w += bfhi(v0.w) + bfhi(v1.w);
  }
  if (j < ee) {
    unsigned s0 = sorted[j] & 0x1FFFF;
    uint4 v0 = yh4[(size_t)s0 * 4 + q4];
    accA.x += bflo(v0.x); accA.y += bfhi(v0.x);
    accA.z += bflo(v0.y); accA.w += bfhi(v0.y);
    accB.x += bflo(v0.z); accB.y += bfhi(v0.z);
    accB.z += bflo(v0.w); accB.w += bfhi(v0.w);
  }
  ((float4*)out)[(size_t)node * 8 + q4 * 2] = accA;
  ((float4*)out)[(size_t)node * 8 + q4 * 2 + 1] = accB;
}

// ---------- prep: zero bucket counters + work-stealing counters ----------
__global__ __launch_bounds__(256) void gin_prep(int* __restrict__ gcount,
                                                int* __restrict__ wc) {
  int i = blockIdx.x * 256 + threadIdx.x;
  if (i < NB) gcount[i] = 0;
  if (i < 2) wc[i] = 0;
}

// ---------- single cooperative persistent kernel ----------
// Phase A: work-stealing over (391 partition + 1563 proj) units -> partition
// latency chains overlap proj streaming. grid.sync. Phase B: work-stealing over
// 1564 gather quarter-units. LDS overlaid: partition 4.7 KB / gather 26.8 KB.
__global__ void __launch_bounds__(256) gin_coop(
    const float* __restrict__ x, const float* __restrict__ W,
    float* __restrict__ y, unsigned short* __restrict__ yh,
    const int* __restrict__ src, const int* __restrict__ dst,
    int* __restrict__ gcount, unsigned* __restrict__ bucketed,
    const float* __restrict__ bias, float* __restrict__ out,
    int* __restrict__ wc, int E, int GBr) {
  __shared__ __align__(16) char shraw[27648];
  __shared__ int s_unit;
  int tid = threadIdx.x;
  int* p_cnt = (int*)shraw;                 // [NB]
  int* p_cur = p_cnt + NB;                  // [NB]
  int* p_gbase = p_cur + NB;                // [NB]
  unsigned* g_stage = (unsigned*)shraw;     // [CAPB]
  unsigned* g_sorted = g_stage + CAPB;      // [GCAP]
  int* g_cnt = (int*)(g_sorted + GCAP);     // [64]
  int* g_off = g_cnt + 64;                  // [65]
  int* g_cur = g_off + 65;                  // [64]
  int totalA = GBr + PUNITS;

  // -------- phase A --------
  while (true) {
    if (tid == 0) s_unit = atomicAdd(&wc[0], 1);
    __syncthreads();
    int u = s_unit;
    __syncthreads();   // all waves consumed u before tid0 can overwrite
    if (u >= totalA) break;
    if (u < GBr)
      partition_unit(u, tid, E, src, dst, gcount, bucketed, p_cnt, p_cur, p_gbase);
    else
      proj_unit(u - GBr, tid, x, W, y, yh);
  }

  __threadfence();
  cg::this_grid().sync();
  __threadfence();

  // -------- phase B --------
  while (true) {
    if (tid == 0) s_unit = atomicAdd(&wc[1], 1);
    __syncthreads();
    int gu = s_unit;
    __syncthreads();
    if (gu >= NGU) break;
    gather_unit(gu, tid, gcount, bucketed, y, yh, bias, out,
                g_stage, g_sorted, g_cnt, g_off, g_cur);
  }
}

// ---------- classic (non-cooperative) path: same device functions ----------
__global__ void __launch_bounds__(256) gin_mid_classic(
    const float* __restrict__ x, const float* __restrict__ W,
    float* __restrict__ y, unsigned short* __restrict__ yh,
    const int* __restrict__ src, const int* __restrict__ dst,
    int* __restrict__ gcount, unsigned* __restrict__ bucketed, int E, int GBr) {
  __shared__ int cnt[NB];
  __shared__ int cur[NB];
  __shared__ int gbase[NB];
  int tid = threadIdx.x;
  if ((int)blockIdx.x >= GBr) {
    proj_unit(blockIdx.x - GBr, tid, x, W, y, yh);
    return;
  }
  partition_unit(blockIdx.x, tid, E, src, dst, gcount, bucketed, cnt, cur, gbase);
}

__global__ void __launch_bounds__(256) gin_gather_classic(
    const int* __restrict__ gcount, const unsigned* __restrict__ bucketed,
    const float* __restrict__ y, const unsigned short* __restrict__ yh,
    const float* __restrict__ bias, float* __restrict__ out) {
  __shared__ unsigned stage[CAPB];
  __shared__ unsigned sorted[GCAP];
  __shared__ int cnt[64];
  __shared__ int off[65];
  __shared__ int cur[64];
  gather_unit(blockIdx.x, threadIdx.x, gcount, bucketed, y, yh, bias, out,
              stage, sorted, cnt, off, cur);
}

// ---------- exact fallback: bias init + atomic scatter ----------
__global__ __launch_bounds__(256) void gin_bias_init(
    const float* __restrict__ y, const float* __restrict__ b,
    float* __restrict__ out) {
  int gid = blockIdx.x * 256 + threadIdx.x;
  if (gid < N_NODES * N_CLASSES) out[gid] = y[gid] + b[gid & 31];
}
__global__ __launch_bounds__(256) void gin_scatter_fb(
    const int* __restrict__ src, const int* __restrict__ dst,
    const float* __restrict__ y, float* __restrict__ out, int n_edges) {
  long long gid = (long long)blockIdx.x * 256 + threadIdx.x;
  int e = (int)(gid >> 5);
  int c = (int)(gid & 31);
  if (e >= n_edges) return;
  atomicAdd(&out[(size_t)dst[e] * N_CLASSES + c],
            y[(size_t)src[e] * N_CLASSES + c]);
}

extern "C" void kernel_launch(void* const* d_in, const int* in_sizes, int n_in,
                              void* d_out, int out_size, void* d_ws, size_t ws_size,
                              hipStream_t stream) {
  const float* x = (const float*)d_in[0];
  const int* edge_index = (const int*)d_in[1];
  const float* W = (const float*)d_in[2];
  const float* b = (const float*)d_in[3];
  float* out = (float*)d_out;

  int E = in_sizes[1] / 2;
  const int* src = edge_index;
  const int* dst = edge_index + E;
  int GBr = (E + EPB - 1) / EPB;      // 391 for E=1.6M

  char* ws = (char*)d_ws;
  size_t sz_y = (size_t)N_NODES * N_CLASSES * 4;                    // 12.8 MB
  size_t sz_yh = (((size_t)N_NODES * N_CLASSES * 2) + 15) & ~15ull; // 6.4 MB
  size_t sz_bucketed = (((size_t)NB * CAPB * 4) + 15) & ~15ull;     // 8.0 MB
  size_t sz_gcnt = ((size_t)NB * 4 + 15) & ~15ull;
  size_t sz_wc = 16;

  float* y = (float*)ws;
  unsigned short* yh = (unsigned short*)(ws + sz_y);
  unsigned* bucketed = (unsigned*)(ws + sz_y + sz_yh);
  int* gcount = (int*)(ws + sz_y + sz_yh + sz_bucketed);
  int* wc = (int*)(ws + sz_y + sz_yh + sz_bucketed + sz_gcnt);
  size_t need = sz_y + sz_yh + sz_bucketed + sz_gcnt + sz_wc;

  // capacity guard: CAPB=5120 covers mean E/391 + 8 sigma up to E ~ 1.75M
  bool dense = E > 1750000;

  if (ws_size < need || dense) {
    // exact fallback: proj-only (GBr=0) + bias init + atomic scatter
    gin_mid_classic<<<PUNITS, 256, 0, stream>>>(x, W, y, yh, src, dst,
                                                (int*)ws, (unsigned*)ws, E, 0);
    gin_bias_init<<<(N_NODES * N_CLASSES + 255) / 256, 256, 0, stream>>>(y, b, out);
    long long t2 = (long long)E * N_CLASSES;
    gin_scatter_fb<<<(int)((t2 + 255) / 256), 256, 0, stream>>>(src, dst, y, out, E);
    return;
  }

  gin_prep<<<2, 256, 0, stream>>>(gcount, wc);

  int nbpc = 0;
  hipError_t oe = hipOccupancyMaxActiveBlocksPerMultiprocessor(&nbpc, gin_coop, 256, 0);
  bool launched = false;
  if (oe == hipSuccess && nbpc >= 1) {
    if (nbpc > 5) nbpc = 5;           // LDS bound: 160 KB / 27.6 KB
    int grid = nbpc * 256;            // 256 CUs
    int maxu = GBr + PUNITS;
    if (grid > maxu) grid = maxu;
    void* args[] = {(void*)&x, (void*)&W, (void*)&y, (void*)&yh,
                    (void*)&src, (void*)&dst, (void*)&gcount, (void*)&bucketed,
                    (void*)&b, (void*)&out, (void*)&wc, (void*)&E, (void*)&GBr};
    hipError_t err = hipLaunchCooperativeKernel((const void*)gin_coop,
                                                dim3(grid), dim3(256),
                                                args, 0, stream);
    launched = (err == hipSuccess);
  }
  if (!launched) {
    gin_mid_classic<<<GBr + PUNITS, 256, 0, stream>>>(x, W, y, yh, src, dst,
                                                      gcount, bucketed, E, GBr);
    gin_gather_classic<<<NGU, 256, 0, stream>>>(gcount, bucketed, y, yh, b, out);
  }
}

// Round 8
// 150.763 us; speedup vs baseline: 2.2852x; 2.2852x over previous
//
#include <hip/hip_runtime.h>

#define N_NODES 100000
#define D_FEAT 128
#define N_CLASSES 32
#define BSHIFT 8
#define NB 391            // ceil(100000/256) dst buckets of 256 nodes
#define EPB 4096          // edges per partition block
#define CAPB 5120         // per-bucket region capacity (mean 4092 + >8 sigma)
#define GCAP 1536         // per-quarter sorted capacity (mean 1023 + >8 sigma)

typedef __attribute__((ext_vector_type(8))) short short8;
typedef __attribute__((ext_vector_type(4))) float f32x4;

__device__ __forceinline__ unsigned short f2bf(float f) {
  unsigned u = __float_as_uint(f);
  u += 0x7fffu + ((u >> 16) & 1);   // round-to-nearest-even
  return (unsigned short)(u >> 16);
}

// pack two f32 -> two bf16 (RNE) in one instruction
__device__ __forceinline__ unsigned cvtpk(float lo, float hi) {
  unsigned r;
  asm("v_cvt_pk_bf16_f32 %0, %1, %2" : "=v"(r) : "v"(lo), "v"(hi));
  return r;
}
__device__ __forceinline__ float bflo(unsigned v) { return __uint_as_float(v << 16); }
__device__ __forceinline__ float bfhi(unsigned v) { return __uint_as_float(v & 0xFFFF0000u); }

// ---------- prep: W -> bf16 table + zero bucket counters ----------
__global__ __launch_bounds__(256) void gin_prep(const float* __restrict__ W,
                                                unsigned short* __restrict__ Wb,
                                                int* __restrict__ gcount) {
  int i = blockIdx.x * 256 + threadIdx.x;
  if (i < D_FEAT * N_CLASSES) Wb[i] = f2bf(W[i]);
  if (i < NB) gcount[i] = 0;
}

// ---------- fused mid: blocks [0,GBr) partition edges, rest MFMA projection ----------
// Partition (r5-proven): edges read ONCE into registers -> LDS histogram ->
// reserve global per-bucket ranges (one atomicAdd per (block,bucket); within-
// bucket order irrelevant, so no scan) -> DIRECT scattered store. Runs of ~10.5
// consecutive slots per (block,bucket) are written by one block => ~2x line amp
// (r3's 17x came from 16 writer-blocks/line). LDS 4.7 KB.
// Projection: wave = 16 nodes x 32 classes; writes f32 y (exact self-term) AND
// bf16 yh (gather aggregate table, halves gather's random-read bytes - r6-proven).
__global__ __launch_bounds__(256) void gin_mid(
    const float* __restrict__ x, const unsigned short* __restrict__ Wb,
    float* __restrict__ y, unsigned short* __restrict__ yh,
    const int* __restrict__ src, const int* __restrict__ dst,
    int* __restrict__ gcount, unsigned* __restrict__ bucketed,
    int E, int GBr) {
  __shared__ int cnt[NB];
  __shared__ int cur[NB];
  __shared__ int gbase[NB];
  int tid = threadIdx.x;

  if ((int)blockIdx.x >= GBr) {
    // ================= projection path =================
    int pb = blockIdx.x - GBr;
    int wave = tid >> 6, lane = tid & 63;
    int node_base = pb * 64 + wave * 16;
    if (node_base >= N_NODES) return;
    int m = lane & 15, quad = lane >> 4;

    short8 bfrag[2][4];
#pragma unroll
    for (int cb = 0; cb < 2; ++cb) {
      const unsigned short* wr = Wb + (cb * 16 + m) * D_FEAT + quad * 8;
#pragma unroll
      for (int ks = 0; ks < 4; ++ks)
        bfrag[cb][ks] = *(const short8*)(wr + ks * 32);
    }

    const float* xr = x + (size_t)(node_base + m) * D_FEAT + quad * 8;
    short8 afrag[4];
#pragma unroll
    for (int ks = 0; ks < 4; ++ks) {
      float4 f0 = *(const float4*)(xr + ks * 32);
      float4 f1 = *(const float4*)(xr + ks * 32 + 4);
      union { uint4 u; short8 s; } au;
      au.u.x = cvtpk(f0.x, f0.y);
      au.u.y = cvtpk(f0.z, f0.w);
      au.u.z = cvtpk(f1.x, f1.y);
      au.u.w = cvtpk(f1.z, f1.w);
      afrag[ks] = au.s;
    }

    f32x4 acc0 = {0.f, 0.f, 0.f, 0.f};
    f32x4 acc1 = {0.f, 0.f, 0.f, 0.f};
#pragma unroll
    for (int ks = 0; ks < 4; ++ks) {
      acc0 = __builtin_amdgcn_mfma_f32_16x16x32_bf16(afrag[ks], bfrag[0][ks], acc0, 0, 0, 0);
      acc1 = __builtin_amdgcn_mfma_f32_16x16x32_bf16(afrag[ks], bfrag[1][ks], acc1, 0, 0, 0);
    }

#pragma unroll
    for (int r = 0; r < 4; ++r) {
      int node = node_base + quad * 4 + r;
      y[(size_t)node * N_CLASSES + m] = acc0[r];
      y[(size_t)node * N_CLASSES + 16 + m] = acc1[r];
      unsigned pk = cvtpk(acc0[r], acc1[r]);   // [bf16 col m | bf16 col m+16]
      yh[(size_t)node * N_CLASSES + m] = (unsigned short)(pk & 0xFFFFu);
      yh[(size_t)node * N_CLASSES + 16 + m] = (unsigned short)(pk >> 16);
    }
    return;
  }

  // ================= partition path (4.7 KB LDS) =================
  int blk = blockIdx.x;
  for (int i = tid; i < NB; i += 256) {
    cnt[i] = 0;
    cur[i] = 0;
  }
  __syncthreads();
  int base = blk * EPB;
  bool full = (base + EPB <= E);

  int dv[16];
  unsigned sv[16];
  if (full) {
#pragma unroll
    for (int k = 0; k < 16; ++k) dv[k] = dst[base + k * 256 + tid];
#pragma unroll
    for (int k = 0; k < 16; ++k) sv[k] = (unsigned)src[base + k * 256 + tid];
  } else {
#pragma unroll
    for (int k = 0; k < 16; ++k) {
      int e = base + k * 256 + tid;
      dv[k] = (e < E) ? dst[e] : -1;
      sv[k] = (e < E) ? (unsigned)src[e] : 0u;
    }
  }
#pragma unroll
  for (int k = 0; k < 16; ++k)
    if (dv[k] >= 0) atomicAdd(&cnt[dv[k] >> BSHIFT], 1);
  __syncthreads();

  for (int i = tid; i < NB; i += 256) {
    int c = cnt[i];
    gbase[i] = c ? atomicAdd(&gcount[i], c) : 0;
  }
  __syncthreads();

#pragma unroll
  for (int k = 0; k < 16; ++k) {
    if (dv[k] >= 0) {
      int b = dv[k] >> BSHIFT;
      int r = atomicAdd(&cur[b], 1);
      int ga = gbase[b] + r;
      if (ga < CAPB)
        bucketed[(size_t)b * CAPB + ga] = sv[k] | ((unsigned)(dv[k] & 255) << 17);
    }
  }
}

// ---------- gather: 4 blocks/bucket; one global pass (stage+count), LDS ----------
// counting-scatter, then 8-threads-per-node accumulation from bf16 yh (uint2 =
// 8 B per neighbor per thread; the 8 q-threads cover the 64 B row contiguously).
// Self-term from f32 y. out = agg + y + b.
__global__ __launch_bounds__(512) void gin_gather_s(
    const int* __restrict__ gcount, const unsigned* __restrict__ bucketed,
    const float* __restrict__ y, const unsigned short* __restrict__ yh,
    const float* __restrict__ bias, float* __restrict__ out) {
  __shared__ unsigned stage[CAPB];   // 20 KB
  __shared__ unsigned sorted[GCAP];  // 6 KB
  __shared__ int cnt[64];
  __shared__ int off[65];
  __shared__ int cur[64];
  int tid = threadIdx.x;
  int bk = blockIdx.x >> 2;
  int qq = blockIdx.x & 3;
  int len = gcount[bk];
  if (len > CAPB) len = CAPB;
  const unsigned* bb = bucketed + (size_t)bk * CAPB;
  if (tid < 64) cnt[tid] = 0;
  __syncthreads();
  // single global pass: stage + count own quarter
  for (int i = tid; i < len; i += 512) {
    unsigned p = bb[i];
    stage[i] = p;
    int n8 = (int)((p >> 17) & 255u);
    if ((n8 >> 6) == qq) atomicAdd(&cnt[n8 & 63], 1);
  }
  __syncthreads();
  if (tid == 0) off[0] = 0;
  if (tid < 64) off[tid + 1] = cnt[tid];
  __syncthreads();
  for (int o = 1; o < 64; o <<= 1) {
    int v = (tid < 64 && tid >= o) ? off[tid + 1 - o] : 0;
    __syncthreads();
    if (tid < 64) off[tid + 1] += v;
    __syncthreads();
  }
  if (tid < 64) cur[tid] = off[tid];
  __syncthreads();
  // LDS -> LDS counting-scatter (no global re-read)
  for (int i = tid; i < len; i += 512) {
    unsigned p = stage[i];
    int n8 = (int)((p >> 17) & 255u);
    if ((n8 >> 6) == qq) {
      int pos = atomicAdd(&cur[n8 & 63], 1);
      if (pos < GCAP) sorted[pos] = p;
    }
  }
  __syncthreads();
  // accumulate: 8 threads per node, thread q owns classes 4q..4q+3
  int nl = tid >> 3;                 // node-in-quarter 0..63
  int q = tid & 7;
  int es = off[nl], ee = off[nl + 1];
  if (ee > GCAP) ee = GCAP;
  if (es > ee) es = ee;
  int node = (bk << 8) + (qq << 6) + nl;
  if (node >= N_NODES) return;
  const float4* y4 = (const float4*)y;
  const unsigned* yh2 = (const unsigned*)yh;   // row stride 16 uints
  float4 bq = ((const float4*)bias)[q];
  float4 self = y4[(size_t)node * 8 + q];
  float4 acc;
  acc.x = self.x + bq.x;
  acc.y = self.y + bq.y;
  acc.z = self.z + bq.z;
  acc.w = self.w + bq.w;
  int j = es;
  for (; j + 4 <= ee; j += 4) {
    unsigned s0 = sorted[j] & 0x1FFFF, s1 = sorted[j + 1] & 0x1FFFF;
    unsigned s2 = sorted[j + 2] & 0x1FFFF, s3 = sorted[j + 3] & 0x1FFFF;
    uint2 v0 = *(const uint2*)(yh2 + (size_t)s0 * 16 + q * 2);
    uint2 v1 = *(const uint2*)(yh2 + (size_t)s1 * 16 + q * 2);
    uint2 v2 = *(const uint2*)(yh2 + (size_t)s2 * 16 + q * 2);
    uint2 v3 = *(const uint2*)(yh2 + (size_t)s3 * 16 + q * 2);
    acc.x += bflo(v0.x) + bflo(v1.x) + bflo(v2.x) + bflo(v3.x);
    acc.y += bfhi(v0.x) + bfhi(v1.x) + bfhi(v2.x) + bfhi(v3.x);
    acc.z += bflo(v0.y) + bflo(v1.y) + bflo(v2.y) + bflo(v3.y);
    acc.w += bfhi(v0.y) + bfhi(v1.y) + bfhi(v2.y) + bfhi(v3.y);
  }
  for (; j < ee; ++j) {
    unsigned s = sorted[j] & 0x1FFFF;
    uint2 v = *(const uint2*)(yh2 + (size_t)s * 16 + q * 2);
    acc.x += bflo(v.x);
    acc.y += bfhi(v.x);
    acc.z += bflo(v.y);
    acc.w += bfhi(v.y);
  }
  ((float4*)out)[(size_t)node * 8 + q] = acc;
}

// ---------- exact fallback: bias init + atomic scatter (f32 y) ----------
__global__ __launch_bounds__(256) void gin_bias_init(
    const float* __restrict__ y, const float* __restrict__ b,
    float* __restrict__ out) {
  int gid = blockIdx.x * 256 + threadIdx.x;
  if (gid < N_NODES * N_CLASSES) out[gid] = y[gid] + b[gid & 31];
}
__global__ __launch_bounds__(256) void gin_scatter_fb(
    const int* __restrict__ src, const int* __restrict__ dst,
    const float* __restrict__ y, float* __restrict__ out, int n_edges) {
  long long gid = (long long)blockIdx.x * 256 + threadIdx.x;
  int e = (int)(gid >> 5);
  int c = (int)(gid & 31);
  if (e >= n_edges) return;
  atomicAdd(&out[(size_t)dst[e] * N_CLASSES + c],
            y[(size_t)src[e] * N_CLASSES + c]);
}

extern "C" void kernel_launch(void* const* d_in, const int* in_sizes, int n_in,
                              void* d_out, int out_size, void* d_ws, size_t ws_size,
                              hipStream_t stream) {
  const float* x = (const float*)d_in[0];
  const int* edge_index = (const int*)d_in[1];
  const float* W = (const float*)d_in[2];
  const float* b = (const float*)d_in[3];
  float* out = (float*)d_out;

  int E = in_sizes[1] / 2;
  const int* src = edge_index;
  const int* dst = edge_index + E;

  int GBr = (E + EPB - 1) / EPB;      // 391 for E=1.6M
  int pblocks = (N_NODES + 63) / 64;  // 1563 projection blocks

  char* ws = (char*)d_ws;
  size_t sz_y = (size_t)N_NODES * N_CLASSES * 4;                    // 12.8 MB
  size_t sz_yh = (((size_t)N_NODES * N_CLASSES * 2) + 15) & ~15ull; // 6.4 MB
  size_t sz_wb = (D_FEAT * N_CLASSES * 2 + 15) & ~15ull;            // 8 KB bf16 W
  size_t sz_bucketed = (((size_t)NB * CAPB * 4) + 15) & ~15ull;     // 8.0 MB
  size_t sz_gcnt = ((size_t)NB * 4 + 15) & ~15ull;

  float* y = (float*)ws;
  unsigned short* yh = (unsigned short*)(ws + sz_y);
  unsigned short* Wb = (unsigned short*)(ws + sz_y + sz_yh);
  unsigned* bucketed = (unsigned*)(ws + sz_y + sz_yh + sz_wb);
  int* gcount = (int*)(ws + sz_y + sz_yh + sz_wb + sz_bucketed);
  size_t need = sz_y + sz_yh + sz_wb + sz_bucketed + sz_gcnt;

  // capacity guard: CAPB=5120 covers mean E/391 + 8 sigma up to E ~ 1.75M
  bool dense = E > 1750000;

  if (ws_size < need || dense) {
    gin_prep<<<16, 256, 0, stream>>>(W, Wb, (int*)ws);  // scratch; y overwritten next
    gin_mid<<<pblocks, 256, 0, stream>>>(x, Wb, y, yh, src, dst,
                                         (int*)ws, (unsigned*)ws, E, 0);
    gin_bias_init<<<(N_NODES * N_CLASSES + 255) / 256, 256, 0, stream>>>(y, b, out);
    long long t2 = (long long)E * N_CLASSES;
    gin_scatter_fb<<<(int)((t2 + 255) / 256), 256, 0, stream>>>(src, dst, y, out, E);
    return;
  }

  gin_prep<<<16, 256, 0, stream>>>(W, Wb, gcount);
  gin_mid<<<GBr + pblocks, 256, 0, stream>>>(x, Wb, y, yh, src, dst,
                                             gcount, bucketed, E, GBr);
  gin_gather_s<<<NB * 4, 512, 0, stream>>>(gcount, bucketed, y, yh, b, out);
}